// Round 1
// baseline (5878.828 us; speedup 1.0000x reference)
//
#include <hip/hip_runtime.h>
#include <hip/hip_bf16.h>

#define NUM_GRAPHS 1024
#define H 128
#define NCLS 10
#define BN_EPS 1e-5f
#define SLOPE 0.01f

__device__ __forceinline__ float leaky(float v) { return v > 0.f ? v : SLOPE * v; }

// ---------------- scatter-add: agg[dst] += (affine?) X[src] --------------------
template<bool AFFINE>
__global__ __launch_bounds__(256)
void scatter_kernel(const float4* __restrict__ X, const int* __restrict__ src,
                    const int* __restrict__ dst, float* __restrict__ agg,
                    const float* __restrict__ ab, int E)
{
    int idx = blockIdx.x * 256 + threadIdx.x;   // (edge, feature-quad)
    int e = idx >> 5;
    int c4 = idx & 31;
    if (e >= E) return;
    int s = src[e];
    int d = dst[e];
    float4 v = X[(size_t)s * 32 + c4];
    if (AFFINE) {
        const float4* ab4 = (const float4*)ab;
        float4 a = ab4[c4];
        float4 b = ab4[32 + c4];
        v.x = fmaf(a.x, v.x, b.x);
        v.y = fmaf(a.y, v.y, b.y);
        v.z = fmaf(a.z, v.z, b.z);
        v.w = fmaf(a.w, v.w, b.w);
    }
    float* out = agg + (size_t)d * 128 + c4 * 4;
    atomicAdd(out + 0, v.x);
    atomicAdd(out + 1, v.y);
    atomicAdd(out + 2, v.z);
    atomicAdd(out + 3, v.w);
}

// ---------------- GEMM: Out = leaky(A @ W + bias), A is [N,128], W [128,128] ----
// AMODE 0: A = A0
// AMODE 1: A = A0 + A1
// AMODE 2: A = alpha[f]*A0 + beta[f] + A1   (per-feature affine, f = k index)
// STATS: accumulate per-feature sum / sumsq of outputs into stat_sum/stat_sq
#define BK 32
#define BMP 132   // padded LDS row stride

template<int AMODE, bool STATS>
__global__ __launch_bounds__(256)
void gemm128(const float* __restrict__ A0, const float* __restrict__ A1,
             const float* __restrict__ ab,
             const float* __restrict__ W, const float* __restrict__ bias,
             float* __restrict__ Out, float* __restrict__ stat_sum,
             float* __restrict__ stat_sq, int N)
{
    __shared__ float As[BK * BMP];   // As[k][m] (transposed tile)
    __shared__ float Ws[BK * BMP];   // Ws[k][c]
    __shared__ float ssum[128];
    __shared__ float ssq[128];

    const int t  = threadIdx.x;
    const int tx = t & 15;    // col group (8 cols)
    const int ty = t >> 4;    // row group (8 rows)
    const int row0 = blockIdx.x * 128;

    const int kStage = t & 31;   // k within chunk
    const int gStage = t >> 5;   // 0..7 (4-row group)

    float acc[8][8];
#pragma unroll
    for (int i = 0; i < 8; i++)
#pragma unroll
        for (int j = 0; j < 8; j++) acc[i][j] = 0.f;

    for (int kc = 0; kc < 128; kc += BK) {
        if (kc) __syncthreads();
        // stage W chunk [32 x 128], direct copy, b128 writes
#pragma unroll
        for (int p = 0; p < 4; ++p) {
            int l  = t + 256 * p;          // 0..1023 float4s
            int kk = l >> 5;
            int c4 = l & 31;
            float4 w = *(const float4*)&W[(size_t)(kc + kk) * 128 + c4 * 4];
            *(float4*)&Ws[kk * BMP + c4 * 4] = w;
        }
        // stage A chunk transposed: As[k][r]
#pragma unroll
        for (int p = 0; p < 4; ++p) {
            int rbase = p * 32 + gStage * 4;
            float tmp[4];
#pragma unroll
            for (int j = 0; j < 4; ++j) {
                int r = row0 + rbase + j;
                float x = 0.f;
                if (r < N) {
                    size_t off = (size_t)r * 128 + kc + kStage;
                    x = A0[off];
                    if (AMODE == 1) x += A1[off];
                    if (AMODE == 2)
                        x = fmaf(ab[kc + kStage], x, ab[128 + kc + kStage]) + A1[off];
                }
                tmp[j] = x;
            }
            *(float4*)&As[kStage * BMP + rbase] =
                make_float4(tmp[0], tmp[1], tmp[2], tmp[3]);
        }
        __syncthreads();
#pragma unroll
        for (int k = 0; k < BK; ++k) {
            const float4 a0 = *(const float4*)&As[k * BMP + ty * 8];
            const float4 a1 = *(const float4*)&As[k * BMP + ty * 8 + 4];
            const float4 w0 = *(const float4*)&Ws[k * BMP + tx * 8];
            const float4 w1 = *(const float4*)&Ws[k * BMP + tx * 8 + 4];
            float a[8] = {a0.x, a0.y, a0.z, a0.w, a1.x, a1.y, a1.z, a1.w};
            float w[8] = {w0.x, w0.y, w0.z, w0.w, w1.x, w1.y, w1.z, w1.w};
#pragma unroll
            for (int i = 0; i < 8; i++)
#pragma unroll
                for (int j = 0; j < 8; j++)
                    acc[i][j] = fmaf(a[i], w[j], acc[i][j]);
        }
    }

    float bv[8];
#pragma unroll
    for (int j = 0; j < 8; j++) bv[j] = bias[tx * 8 + j];

    float colsum[8], colsq[8];
#pragma unroll
    for (int j = 0; j < 8; j++) { colsum[j] = 0.f; colsq[j] = 0.f; }

#pragma unroll
    for (int i = 0; i < 8; i++) {
        int r = row0 + ty * 8 + i;
        if (r < N) {
            float o[8];
#pragma unroll
            for (int j = 0; j < 8; j++) {
                float v = leaky(acc[i][j] + bv[j]);
                o[j] = v;
                if (STATS) { colsum[j] += v; colsq[j] += v * v; }
            }
            *(float4*)&Out[(size_t)r * 128 + tx * 8]     = make_float4(o[0], o[1], o[2], o[3]);
            *(float4*)&Out[(size_t)r * 128 + tx * 8 + 4] = make_float4(o[4], o[5], o[6], o[7]);
        }
    }

    if (STATS) {
        __syncthreads();
        if (t < 128) { ssum[t] = 0.f; ssq[t] = 0.f; }
        __syncthreads();
#pragma unroll
        for (int j = 0; j < 8; j++) {
            atomicAdd(&ssum[tx * 8 + j], colsum[j]);
            atomicAdd(&ssq[tx * 8 + j], colsq[j]);
        }
        __syncthreads();
        if (t < 128) {
            atomicAdd(&stat_sum[t], ssum[t]);
            atomicAdd(&stat_sq[t], ssq[t]);
        }
    }
}

// ---------------- BN finalize: alpha = g*rsqrt(var+eps), beta' = be - alpha*mean -
__global__ void finalize_bn(const float* __restrict__ sum, const float* __restrict__ sq,
                            const float* __restrict__ g, const float* __restrict__ be,
                            float* __restrict__ ab, int N)
{
    int f = threadIdx.x;
    float invN = 1.f / (float)N;
    float mean = sum[f] * invN;
    float var  = sq[f] * invN - mean * mean;
    float a = g[f] * rsqrtf(var + BN_EPS);
    ab[f]       = a;
    ab[128 + f] = be[f] - a * mean;
}

// ---------------- pool: hg[g] = alpha2*sum_nodes(H2) + cnt*beta2 ----------------
__device__ __forceinline__ int lower_bound(const int* b, int n, int v)
{
    int lo = 0, hi = n;
    while (lo < hi) { int mid = (lo + hi) >> 1; if (b[mid] < v) lo = mid + 1; else hi = mid; }
    return lo;
}

__global__ __launch_bounds__(128)
void pool_kernel(const float* __restrict__ Hn, const int* __restrict__ batch,
                 const float* __restrict__ ab2, float* __restrict__ hg, int N)
{
    int g = blockIdx.x;
    int f = threadIdx.x;
    __shared__ int ss, se;
    if (f == 0) {
        ss = lower_bound(batch, N, g);
        se = lower_bound(batch, N, g + 1);
    }
    __syncthreads();
    float acc = 0.f;
    for (int i = ss; i < se; ++i) acc += Hn[(size_t)i * 128 + f];
    float cnt = (float)(se - ss);
    hg[(size_t)g * 128 + f] = fmaf(ab2[f], acc, cnt * ab2[128 + f]);
}

// ---------------- head: per-graph 2-layer MLP + log_softmax ---------------------
__global__ __launch_bounds__(128)
void head_kernel(const float* __restrict__ hg, const float* __restrict__ fcW1,
                 const float* __restrict__ fcb1, const float* __restrict__ fcW2,
                 const float* __restrict__ fcb2, float* __restrict__ out)
{
    int g = blockIdx.x;
    int t = threadIdx.x;
    __shared__ float row[128];
    __shared__ float z1[128];
    row[t] = hg[(size_t)g * 128 + t];
    __syncthreads();
    float acc = fcb1[t];
#pragma unroll 8
    for (int k = 0; k < 128; ++k) acc = fmaf(row[k], fcW1[(size_t)k * 128 + t], acc);
    z1[t] = leaky(acc);
    __syncthreads();
    if (t < 64) {
        float lg[NCLS];
#pragma unroll
        for (int c = 0; c < NCLS; ++c) {
            float p = z1[t] * fcW2[t * NCLS + c] + z1[t + 64] * fcW2[(t + 64) * NCLS + c];
#pragma unroll
            for (int off = 32; off > 0; off >>= 1) p += __shfl_down(p, off, 64);
            if (t == 0) lg[c] = p + fcb2[c];
        }
        if (t == 0) {
            float m = lg[0];
#pragma unroll
            for (int c = 1; c < NCLS; ++c) m = fmaxf(m, lg[c]);
            float s = 0.f;
#pragma unroll
            for (int c = 0; c < NCLS; ++c) s += expf(lg[c] - m);
            float lse = logf(s);
#pragma unroll
            for (int c = 0; c < NCLS; ++c) out[(size_t)g * NCLS + c] = lg[c] - m - lse;
        }
    }
}

// ---------------- launch --------------------------------------------------------
extern "C" void kernel_launch(void* const* d_in, const int* in_sizes, int n_in,
                              void* d_out, int out_size, void* d_ws, size_t ws_size,
                              hipStream_t stream)
{
    const float* x    = (const float*)d_in[0];
    const float* W1a  = (const float*)d_in[1];
    const float* b1a  = (const float*)d_in[2];
    const float* W1b  = (const float*)d_in[3];
    const float* b1b  = (const float*)d_in[4];
    const float* g1   = (const float*)d_in[5];
    const float* be1  = (const float*)d_in[6];
    const float* W2a  = (const float*)d_in[7];
    const float* b2a  = (const float*)d_in[8];
    const float* W2b  = (const float*)d_in[9];
    const float* b2b  = (const float*)d_in[10];
    const float* g2   = (const float*)d_in[11];
    const float* be2  = (const float*)d_in[12];
    const float* fcW1 = (const float*)d_in[13];
    const float* fcb1 = (const float*)d_in[14];
    const float* fcW2 = (const float*)d_in[15];
    const float* fcb2 = (const float*)d_in[16];
    const int*   edge = (const int*)d_in[17];
    const int*   batch= (const int*)d_in[18];

    const int N = in_sizes[0] / 128;
    const int E = in_sizes[17] / 2;
    const int* src = edge;
    const int* dst = edge + E;

    const size_t NH = (size_t)N * 128;
    float* ws   = (float*)d_ws;
    float* agg  = ws;
    float* bufB = ws + NH;
    float* bufC = bufB + NH;
    float* stats= bufC + NH;      // sum1,sq1,sum2,sq2 (4*128)
    float* sum1 = stats;
    float* sq1  = stats + 128;
    float* sum2 = stats + 256;
    float* sq2  = stats + 384;
    float* ab1  = stats + 512;    // alpha1[128], beta1[128]
    float* ab2  = ab1 + 256;
    float* hg   = ab2 + 256;      // [1024,128]

    const int scatterBlocks = (int)(((long long)E * 32 + 255) / 256);
    const int gemmBlocks    = (N + 127) / 128;

    hipMemsetAsync(agg, 0, NH * sizeof(float), stream);
    hipMemsetAsync(stats, 0, 512 * sizeof(float), stream);

    // conv1
    scatter_kernel<false><<<scatterBlocks, 256, 0, stream>>>(
        (const float4*)x, src, dst, agg, nullptr, E);
    gemm128<1, false><<<gemmBlocks, 256, 0, stream>>>(
        x, agg, nullptr, W1a, b1a, bufB, nullptr, nullptr, N);
    gemm128<0, true><<<gemmBlocks, 256, 0, stream>>>(
        bufB, nullptr, nullptr, W1b, b1b, bufC, sum1, sq1, N);
    finalize_bn<<<1, 128, 0, stream>>>(sum1, sq1, g1, be1, ab1, N);

    // conv2 (BN1 applied on the fly via ab1 affine)
    hipMemsetAsync(agg, 0, NH * sizeof(float), stream);
    scatter_kernel<true><<<scatterBlocks, 256, 0, stream>>>(
        (const float4*)bufC, src, dst, agg, ab1, E);
    gemm128<2, false><<<gemmBlocks, 256, 0, stream>>>(
        bufC, agg, ab1, W2a, b2a, bufB, nullptr, nullptr, N);
    gemm128<0, true><<<gemmBlocks, 256, 0, stream>>>(
        bufB, nullptr, nullptr, W2b, b2b, bufC, sum2, sq2, N);
    finalize_bn<<<1, 128, 0, stream>>>(sum2, sq2, g2, be2, ab2, N);

    // pool (BN2 folded in) + head
    pool_kernel<<<NUM_GRAPHS, 128, 0, stream>>>(bufC, batch, ab2, hg, N);
    head_kernel<<<NUM_GRAPHS, 128, 0, stream>>>(hg, fcW1, fcb1, fcW2, fcb2, (float*)d_out);
}

// Round 2
// 892.024 us; speedup vs baseline: 6.5904x; 6.5904x over previous
//
#include <hip/hip_runtime.h>
#include <hip/hip_bf16.h>

#define NUM_GRAPHS 1024
#define NCLS 10
#define BN_EPS 1e-5f
#define SLOPE 0.01f

__device__ __forceinline__ float leaky(float v) { return v > 0.f ? v : SLOPE * v; }

// ================= CSR build ====================================================
__global__ __launch_bounds__(256)
void count_kernel(const int* __restrict__ dst, int* __restrict__ deg, int E)
{
    int e = blockIdx.x * 256 + threadIdx.x;
    if (e < E) atomicAdd(&deg[dst[e]], 1);
}

// block scans 1024 elements (256 thr x 4); writes local-exclusive prefix + block sum
__global__ __launch_bounds__(256)
void scan_block_kernel(const int* __restrict__ deg, int* __restrict__ rowptr,
                       int* __restrict__ blockSums, int N)
{
    __shared__ int wsum[4];
    int t = threadIdx.x;
    int base = blockIdx.x * 1024 + t * 4;
    int v0 = 0, v1 = 0, v2 = 0, v3 = 0;
    if (base + 3 < N) {
        int4 q = *(const int4*)&deg[base];
        v0 = q.x; v1 = q.y; v2 = q.z; v3 = q.w;
    } else {
        if (base + 0 < N) v0 = deg[base + 0];
        if (base + 1 < N) v1 = deg[base + 1];
        if (base + 2 < N) v2 = deg[base + 2];
    }
    int t1 = v0 + v1, t2 = t1 + v2, t3 = t2 + v3;   // thread-local inclusives
    int lane = t & 63, w = t >> 6;
    int x = t3;
#pragma unroll
    for (int off = 1; off < 64; off <<= 1) {
        int y = __shfl_up(x, off, 64);
        if (lane >= off) x += y;
    }
    if (lane == 63) wsum[w] = x;
    __syncthreads();
    if (t == 0) {
        int a = 0;
#pragma unroll
        for (int i = 0; i < 4; i++) { int s = wsum[i]; wsum[i] = a; a += s; }
        blockSums[blockIdx.x] = a;
    }
    __syncthreads();
    int excl = x - t3 + wsum[w];
    int4 o; o.x = excl; o.y = excl + v0; o.z = excl + t1; o.w = excl + t2;
    if (base + 3 < N) *(int4*)&rowptr[base] = o;
    else {
        if (base + 0 < N) rowptr[base + 0] = o.x;
        if (base + 1 < N) rowptr[base + 1] = o.y;
        if (base + 2 < N) rowptr[base + 2] = o.z;
    }
}

// exclusive scan of <=128 block sums, in place (LDS-staged)
__global__ void scan_sums_kernel(int* __restrict__ blockSums, int nb)
{
    __shared__ int s[128];
    int t = threadIdx.x;
    s[t] = (t < nb) ? blockSums[t] : 0;
    __syncthreads();
    if (t == 0) { int a = 0; for (int i = 0; i < nb; i++) { int v = s[i]; s[i] = a; a += v; } }
    __syncthreads();
    if (t < nb) blockSums[t] = s[t];
}

__global__ __launch_bounds__(256)
void add_offsets_kernel(int* __restrict__ rowptr, int* __restrict__ cursor,
                        const int* __restrict__ blockSums, int N, int E)
{
    int i = blockIdx.x * 256 + threadIdx.x;
    if (i < N) {
        int r = rowptr[i] + blockSums[i >> 10];
        rowptr[i] = r;
        cursor[i] = r;
    }
    if (i == 0) rowptr[N] = E;
}

__global__ __launch_bounds__(256)
void fill_kernel(const int* __restrict__ src, const int* __restrict__ dst,
                 int* __restrict__ cursor, int* __restrict__ csr_src, int E)
{
    int e = blockIdx.x * 256 + threadIdx.x;
    if (e < E) {
        int slot = atomicAdd(&cursor[dst[e]], 1);
        csr_src[slot] = src[e];
    }
}

// ================= gather: out[i] = f(X[i]) + sum_{j->i} f(X[j]) ================
// f = identity (AFFINE=false) or per-feature a*x+b (AFFINE=true, BN fold)
template<bool AFFINE>
__global__ __launch_bounds__(256)
void gather_kernel(const float4* __restrict__ X, const int* __restrict__ rowptr,
                   const int* __restrict__ csr_src, const float* __restrict__ ab,
                   float4* __restrict__ out, int N)
{
    int node = blockIdx.x * 8 + (threadIdx.x >> 5);
    int c4 = threadIdx.x & 31;
    if (node >= N) return;

    float4 a, b;
    if (AFFINE) {
        a = ((const float4*)ab)[c4];
        b = ((const float4*)ab)[32 + c4];
    }
    float4 v = X[(size_t)node * 32 + c4];
    float4 acc;
    if (AFFINE) acc = make_float4(fmaf(a.x, v.x, b.x), fmaf(a.y, v.y, b.y),
                                  fmaf(a.z, v.z, b.z), fmaf(a.w, v.w, b.w));
    else acc = v;

    int s = rowptr[node], e = rowptr[node + 1];
    int i = s;
    for (; i + 1 < e; i += 2) {
        int j0 = csr_src[i], j1 = csr_src[i + 1];
        float4 u0 = X[(size_t)j0 * 32 + c4];
        float4 u1 = X[(size_t)j1 * 32 + c4];
        if (AFFINE) {
            acc.x += fmaf(a.x, u0.x, b.x) + fmaf(a.x, u1.x, b.x);
            acc.y += fmaf(a.y, u0.y, b.y) + fmaf(a.y, u1.y, b.y);
            acc.z += fmaf(a.z, u0.z, b.z) + fmaf(a.z, u1.z, b.z);
            acc.w += fmaf(a.w, u0.w, b.w) + fmaf(a.w, u1.w, b.w);
        } else {
            acc.x += u0.x + u1.x;
            acc.y += u0.y + u1.y;
            acc.z += u0.z + u1.z;
            acc.w += u0.w + u1.w;
        }
    }
    if (i < e) {
        int j0 = csr_src[i];
        float4 u0 = X[(size_t)j0 * 32 + c4];
        if (AFFINE) {
            acc.x += fmaf(a.x, u0.x, b.x);
            acc.y += fmaf(a.y, u0.y, b.y);
            acc.z += fmaf(a.z, u0.z, b.z);
            acc.w += fmaf(a.w, u0.w, b.w);
        } else {
            acc.x += u0.x; acc.y += u0.y; acc.z += u0.z; acc.w += u0.w;
        }
    }
    out[(size_t)node * 32 + c4] = acc;
}

// ================= GEMM: Out = leaky(A @ W + bias) ==============================
#define BK 32
#define BMP 132   // padded LDS row stride

template<bool STATS>
__global__ __launch_bounds__(256)
void gemm128(const float* __restrict__ A0, const float* __restrict__ W,
             const float* __restrict__ bias, float* __restrict__ Out,
             float* __restrict__ stat_sum, float* __restrict__ stat_sq, int N)
{
    __shared__ float As[BK * BMP];   // As[k][m] (transposed tile)
    __shared__ float Ws[BK * BMP];   // Ws[k][c]
    __shared__ float ssum[128];
    __shared__ float ssq[128];

    const int t  = threadIdx.x;
    const int tx = t & 15;    // col group (8 cols)
    const int ty = t >> 4;    // row group (8 rows)
    const int row0 = blockIdx.x * 128;

    const int kStage = t & 31;   // k within chunk
    const int gStage = t >> 5;   // 0..7 (4-row group)

    float acc[8][8];
#pragma unroll
    for (int i = 0; i < 8; i++)
#pragma unroll
        for (int j = 0; j < 8; j++) acc[i][j] = 0.f;

    for (int kc = 0; kc < 128; kc += BK) {
        if (kc) __syncthreads();
#pragma unroll
        for (int p = 0; p < 4; ++p) {
            int l  = t + 256 * p;
            int kk = l >> 5;
            int c4 = l & 31;
            float4 w = *(const float4*)&W[(size_t)(kc + kk) * 128 + c4 * 4];
            *(float4*)&Ws[kk * BMP + c4 * 4] = w;
        }
#pragma unroll
        for (int p = 0; p < 4; ++p) {
            int rbase = p * 32 + gStage * 4;
            float tmp[4];
#pragma unroll
            for (int j = 0; j < 4; ++j) {
                int r = row0 + rbase + j;
                float x = 0.f;
                if (r < N) x = A0[(size_t)r * 128 + kc + kStage];
                tmp[j] = x;
            }
            *(float4*)&As[kStage * BMP + rbase] =
                make_float4(tmp[0], tmp[1], tmp[2], tmp[3]);
        }
        __syncthreads();
#pragma unroll
        for (int k = 0; k < BK; ++k) {
            const float4 a0 = *(const float4*)&As[k * BMP + ty * 8];
            const float4 a1 = *(const float4*)&As[k * BMP + ty * 8 + 4];
            const float4 w0 = *(const float4*)&Ws[k * BMP + tx * 8];
            const float4 w1 = *(const float4*)&Ws[k * BMP + tx * 8 + 4];
            float a[8] = {a0.x, a0.y, a0.z, a0.w, a1.x, a1.y, a1.z, a1.w};
            float w[8] = {w0.x, w0.y, w0.z, w0.w, w1.x, w1.y, w1.z, w1.w};
#pragma unroll
            for (int i = 0; i < 8; i++)
#pragma unroll
                for (int j = 0; j < 8; j++)
                    acc[i][j] = fmaf(a[i], w[j], acc[i][j]);
        }
    }

    float bv[8];
#pragma unroll
    for (int j = 0; j < 8; j++) bv[j] = bias[tx * 8 + j];

    float colsum[8], colsq[8];
#pragma unroll
    for (int j = 0; j < 8; j++) { colsum[j] = 0.f; colsq[j] = 0.f; }

#pragma unroll
    for (int i = 0; i < 8; i++) {
        int r = row0 + ty * 8 + i;
        if (r < N) {
            float o[8];
#pragma unroll
            for (int j = 0; j < 8; j++) {
                float v = leaky(acc[i][j] + bv[j]);
                o[j] = v;
                if (STATS) { colsum[j] += v; colsq[j] += v * v; }
            }
            *(float4*)&Out[(size_t)r * 128 + tx * 8]     = make_float4(o[0], o[1], o[2], o[3]);
            *(float4*)&Out[(size_t)r * 128 + tx * 8 + 4] = make_float4(o[4], o[5], o[6], o[7]);
        }
    }

    if (STATS) {
        __syncthreads();
        if (t < 128) { ssum[t] = 0.f; ssq[t] = 0.f; }
        __syncthreads();
#pragma unroll
        for (int j = 0; j < 8; j++) {
            atomicAdd(&ssum[tx * 8 + j], colsum[j]);
            atomicAdd(&ssq[tx * 8 + j], colsq[j]);
        }
        __syncthreads();
        if (t < 128) {
            atomicAdd(&stat_sum[t], ssum[t]);
            atomicAdd(&stat_sq[t], ssq[t]);
        }
    }
}

// ================= BN finalize ==================================================
__global__ void finalize_bn(const float* __restrict__ sum, const float* __restrict__ sq,
                            const float* __restrict__ g, const float* __restrict__ be,
                            float* __restrict__ ab, int N)
{
    int f = threadIdx.x;
    float invN = 1.f / (float)N;
    float mean = sum[f] * invN;
    float var  = sq[f] * invN - mean * mean;
    float a = g[f] * rsqrtf(var + BN_EPS);
    ab[f]       = a;
    ab[128 + f] = be[f] - a * mean;
}

// ================= pool =========================================================
__device__ __forceinline__ int lower_bound(const int* b, int n, int v)
{
    int lo = 0, hi = n;
    while (lo < hi) { int mid = (lo + hi) >> 1; if (b[mid] < v) lo = mid + 1; else hi = mid; }
    return lo;
}

__global__ __launch_bounds__(128)
void pool_kernel(const float* __restrict__ Hn, const int* __restrict__ batch,
                 const float* __restrict__ ab2, float* __restrict__ hg, int N)
{
    int g = blockIdx.x;
    int f = threadIdx.x;
    __shared__ int ss, se;
    if (f == 0) {
        ss = lower_bound(batch, N, g);
        se = lower_bound(batch, N, g + 1);
    }
    __syncthreads();
    float acc = 0.f;
    for (int i = ss; i < se; ++i) acc += Hn[(size_t)i * 128 + f];
    float cnt = (float)(se - ss);
    hg[(size_t)g * 128 + f] = fmaf(ab2[f], acc, cnt * ab2[128 + f]);
}

// ================= head =========================================================
__global__ __launch_bounds__(128)
void head_kernel(const float* __restrict__ hg, const float* __restrict__ fcW1,
                 const float* __restrict__ fcb1, const float* __restrict__ fcW2,
                 const float* __restrict__ fcb2, float* __restrict__ out)
{
    int g = blockIdx.x;
    int t = threadIdx.x;
    __shared__ float row[128];
    __shared__ float z1[128];
    row[t] = hg[(size_t)g * 128 + t];
    __syncthreads();
    float acc = fcb1[t];
#pragma unroll 8
    for (int k = 0; k < 128; ++k) acc = fmaf(row[k], fcW1[(size_t)k * 128 + t], acc);
    z1[t] = leaky(acc);
    __syncthreads();
    if (t < 64) {
        float lg[NCLS];
#pragma unroll
        for (int c = 0; c < NCLS; ++c) {
            float p = z1[t] * fcW2[t * NCLS + c] + z1[t + 64] * fcW2[(t + 64) * NCLS + c];
#pragma unroll
            for (int off = 32; off > 0; off >>= 1) p += __shfl_down(p, off, 64);
            if (t == 0) lg[c] = p + fcb2[c];
        }
        if (t == 0) {
            float m = lg[0];
#pragma unroll
            for (int c = 1; c < NCLS; ++c) m = fmaxf(m, lg[c]);
            float s = 0.f;
#pragma unroll
            for (int c = 0; c < NCLS; ++c) s += expf(lg[c] - m);
            float lse = logf(s);
#pragma unroll
            for (int c = 0; c < NCLS; ++c) out[(size_t)g * NCLS + c] = lg[c] - m - lse;
        }
    }
}

// ================= launch =======================================================
extern "C" void kernel_launch(void* const* d_in, const int* in_sizes, int n_in,
                              void* d_out, int out_size, void* d_ws, size_t ws_size,
                              hipStream_t stream)
{
    const float* x    = (const float*)d_in[0];
    const float* W1a  = (const float*)d_in[1];
    const float* b1a  = (const float*)d_in[2];
    const float* W1b  = (const float*)d_in[3];
    const float* b1b  = (const float*)d_in[4];
    const float* g1   = (const float*)d_in[5];
    const float* be1  = (const float*)d_in[6];
    const float* W2a  = (const float*)d_in[7];
    const float* b2a  = (const float*)d_in[8];
    const float* W2b  = (const float*)d_in[9];
    const float* b2b  = (const float*)d_in[10];
    const float* g2   = (const float*)d_in[11];
    const float* be2  = (const float*)d_in[12];
    const float* fcW1 = (const float*)d_in[13];
    const float* fcb1 = (const float*)d_in[14];
    const float* fcW2 = (const float*)d_in[15];
    const float* fcb2 = (const float*)d_in[16];
    const int*   edge = (const int*)d_in[17];
    const int*   batch= (const int*)d_in[18];

    const int N = in_sizes[0] / 128;
    const int E = in_sizes[17] / 2;
    const int* src = edge;
    const int* dst = edge + E;

    const size_t NH = (size_t)N * 128;
    float* ws   = (float*)d_ws;
    float* bufA = ws;
    float* bufB = ws + NH;
    float* stats= bufB + NH;          // sum1,sq1,sum2,sq2 (512 floats)
    float* sum1 = stats;
    float* sq1  = stats + 128;
    float* sum2 = stats + 256;
    float* sq2  = stats + 384;
    float* ab1  = stats + 512;        // alpha1,beta1
    float* ab2  = stats + 768;        // alpha2,beta2
    float* hg   = stats + 1024;       // [1024,128]
    int*   iws      = (int*)(hg + (size_t)NUM_GRAPHS * 128);
    int*   rowptr   = iws;                          // N+1 (padded)
    int*   cursor   = rowptr + ((N + 4) & ~3);      // N (16B aligned)
    int*   csr_src  = cursor + ((N + 4) & ~3);      // E
    int*   blockSums= csr_src + ((E + 4) & ~3);     // <=128

    const int edgeBlocks = (E + 255) / 256;
    const int nodeBlocks = (N + 255) / 256;
    const int scanBlocks = (N + 1023) / 1024;       // 98 for N=100000
    const int gatherBlocks = (N + 7) / 8;
    const int gemmBlocks = (N + 127) / 128;

    // --- CSR build (once per call; shared by both convs) ---
    hipMemsetAsync(cursor, 0, (size_t)N * sizeof(int), stream);
    hipMemsetAsync(stats, 0, 512 * sizeof(float), stream);
    count_kernel<<<edgeBlocks, 256, 0, stream>>>(dst, cursor, E);
    scan_block_kernel<<<scanBlocks, 256, 0, stream>>>(cursor, rowptr, blockSums, N);
    scan_sums_kernel<<<1, 128, 0, stream>>>(blockSums, scanBlocks);
    add_offsets_kernel<<<nodeBlocks, 256, 0, stream>>>(rowptr, cursor, blockSums, N, E);
    fill_kernel<<<edgeBlocks, 256, 0, stream>>>(src, dst, cursor, csr_src, E);

    // --- conv1 ---
    gather_kernel<false><<<gatherBlocks, 256, 0, stream>>>(
        (const float4*)x, rowptr, csr_src, nullptr, (float4*)bufA, N);
    gemm128<false><<<gemmBlocks, 256, 0, stream>>>(bufA, W1a, b1a, bufB, nullptr, nullptr, N);
    gemm128<true><<<gemmBlocks, 256, 0, stream>>>(bufB, W1b, b1b, bufA, sum1, sq1, N);
    finalize_bn<<<1, 128, 0, stream>>>(sum1, sq1, g1, be1, ab1, N);

    // --- conv2 (BN1 folded into gather affine) ---
    gather_kernel<true><<<gatherBlocks, 256, 0, stream>>>(
        (const float4*)bufA, rowptr, csr_src, ab1, (float4*)bufB, N);
    gemm128<false><<<gemmBlocks, 256, 0, stream>>>(bufB, W2a, b2a, bufA, nullptr, nullptr, N);
    gemm128<true><<<gemmBlocks, 256, 0, stream>>>(bufA, W2b, b2b, bufB, sum2, sq2, N);
    finalize_bn<<<1, 128, 0, stream>>>(sum2, sq2, g2, be2, ab2, N);

    // --- pool (BN2 folded) + head ---
    pool_kernel<<<NUM_GRAPHS, 128, 0, stream>>>(bufB, batch, ab2, hg, N);
    head_kernel<<<NUM_GRAPHS, 128, 0, stream>>>(hg, fcW1, fcb1, fcW2, fcb2, (float*)d_out);
}

// Round 3
// 592.592 us; speedup vs baseline: 9.9205x; 1.5053x over previous
//
#include <hip/hip_runtime.h>
#include <hip/hip_bf16.h>

#define NUM_GRAPHS 1024
#define NCLS 10
#define BN_EPS 1e-5f
#define SLOPE 0.01f

typedef __attribute__((ext_vector_type(8))) short          bfrag;
typedef __attribute__((ext_vector_type(4))) float          ffrag;
typedef __attribute__((ext_vector_type(8))) unsigned short ushort8;

__device__ __forceinline__ float leaky(float v) { return v > 0.f ? v : SLOPE * v; }

__device__ __forceinline__ unsigned short f2bf(float f) {
    unsigned int u = __float_as_uint(f);
    unsigned int r = (u + 0x7fffu + ((u >> 16) & 1u)) >> 16;
    return (unsigned short)r;
}
__device__ __forceinline__ float bf2f(unsigned short u) {
    return __uint_as_float(((unsigned int)u) << 16);
}

// ================= dtype conversion =============================================
__global__ __launch_bounds__(256)
void cvt_x_kernel(const float* __restrict__ in, unsigned short* __restrict__ out, int n)
{
    int i = (blockIdx.x * 256 + threadIdx.x) * 4;
    if (i + 3 < n) {
        float4 f = *(const float4*)&in[i];
        ushort8 dummy; (void)dummy;
        unsigned short o0 = f2bf(f.x), o1 = f2bf(f.y), o2 = f2bf(f.z), o3 = f2bf(f.w);
        unsigned long long packed = (unsigned long long)o0 | ((unsigned long long)o1 << 16)
                                  | ((unsigned long long)o2 << 32) | ((unsigned long long)o3 << 48);
        *(unsigned long long*)&out[i] = packed;
    } else if (i < n) {
        for (int j = i; j < n; ++j) out[j] = f2bf(in[j]);
    }
}

// transpose + convert 128x128 weights: WT[n][k] = bf16(W[k][n]); blockIdx = weight id
__global__ __launch_bounds__(256)
void cvt_w_kernel(const float* __restrict__ W0, const float* __restrict__ W1,
                  const float* __restrict__ W2, const float* __restrict__ W3,
                  unsigned short* __restrict__ WT)
{
    const float* W = (blockIdx.x == 0) ? W0 : (blockIdx.x == 1) ? W1
                   : (blockIdx.x == 2) ? W2 : W3;
    unsigned short* O = WT + (size_t)blockIdx.x * 16384;
    int t = threadIdx.x;
#pragma unroll
    for (int p = 0; p < 64; ++p) {
        int idx = p * 256 + t;
        int n = idx >> 7, k = idx & 127;
        O[n * 128 + k] = f2bf(W[k * 128 + n]);
    }
}

// ================= CSR build (rank trick: one atomic pass) ======================
__global__ __launch_bounds__(256)
void rank_kernel(const int* __restrict__ dst, int* __restrict__ deg,
                 int* __restrict__ rank, int E)
{
    int e = blockIdx.x * 256 + threadIdx.x;
    if (e < E) rank[e] = atomicAdd(&deg[dst[e]], 1);
}

__global__ __launch_bounds__(256)
void scan_block_kernel(const int* __restrict__ deg, int* __restrict__ rowptr,
                       int* __restrict__ blockSums, int N)
{
    __shared__ int wsum[4];
    int t = threadIdx.x;
    int base = blockIdx.x * 1024 + t * 4;
    int v0 = 0, v1 = 0, v2 = 0, v3 = 0;
    if (base + 3 < N) {
        int4 q = *(const int4*)&deg[base];
        v0 = q.x; v1 = q.y; v2 = q.z; v3 = q.w;
    } else {
        if (base + 0 < N) v0 = deg[base + 0];
        if (base + 1 < N) v1 = deg[base + 1];
        if (base + 2 < N) v2 = deg[base + 2];
    }
    int t1 = v0 + v1, t2 = t1 + v2, t3 = t2 + v3;
    int lane = t & 63, w = t >> 6;
    int x = t3;
#pragma unroll
    for (int off = 1; off < 64; off <<= 1) {
        int y = __shfl_up(x, off, 64);
        if (lane >= off) x += y;
    }
    if (lane == 63) wsum[w] = x;
    __syncthreads();
    if (t == 0) {
        int a = 0;
#pragma unroll
        for (int i = 0; i < 4; i++) { int s = wsum[i]; wsum[i] = a; a += s; }
        blockSums[blockIdx.x] = a;
    }
    __syncthreads();
    int excl = x - t3 + wsum[w];
    int4 o; o.x = excl; o.y = excl + v0; o.z = excl + t1; o.w = excl + t2;
    if (base + 3 < N) *(int4*)&rowptr[base] = o;
    else {
        if (base + 0 < N) rowptr[base + 0] = o.x;
        if (base + 1 < N) rowptr[base + 1] = o.y;
        if (base + 2 < N) rowptr[base + 2] = o.z;
    }
}

__global__ void scan_sums_kernel(int* __restrict__ blockSums, int nb)
{
    __shared__ int s[128];
    int t = threadIdx.x;
    s[t] = (t < nb) ? blockSums[t] : 0;
    __syncthreads();
    if (t == 0) { int a = 0; for (int i = 0; i < nb; i++) { int v = s[i]; s[i] = a; a += v; } }
    __syncthreads();
    if (t < nb) blockSums[t] = s[t];
}

__global__ __launch_bounds__(256)
void add_offsets_kernel(int* __restrict__ rowptr, const int* __restrict__ blockSums,
                        int N, int E)
{
    int i = blockIdx.x * 256 + threadIdx.x;
    if (i < N) rowptr[i] += blockSums[i >> 10];
    if (i == 0) rowptr[N] = E;
}

__global__ __launch_bounds__(256)
void fill_kernel(const int* __restrict__ src, const int* __restrict__ dst,
                 const int* __restrict__ rowptr, const int* __restrict__ rank,
                 int* __restrict__ csr_src, int E)
{
    int e = blockIdx.x * 256 + threadIdx.x;
    if (e < E) {
        int d = dst[e];
        csr_src[rowptr[d] + rank[e]] = src[e];
    }
}

// ================= gather (bf16 in/out, fp32 accum) =============================
// out[i] = f( X[i] + sum_{j->i} X[j] ),  f = identity or a*z + cnt*b (BN fold)
template<bool AFFINE>
__global__ __launch_bounds__(256)
void gather_bf(const unsigned short* __restrict__ X, const int* __restrict__ rowptr,
               const int* __restrict__ csr_src, const float* __restrict__ ab,
               unsigned short* __restrict__ out, int N)
{
    int node = blockIdx.x * 16 + (threadIdx.x >> 4);
    int c8 = (threadIdx.x & 15) * 8;
    if (node >= N) return;

    float acc[8];
    {
        ushort8 v = *(const ushort8*)&X[(size_t)node * 128 + c8];
#pragma unroll
        for (int k = 0; k < 8; ++k) acc[k] = bf2f(v[k]);
    }
    int s = rowptr[node], e = rowptr[node + 1];
    int i = s;
    for (; i + 1 < e; i += 2) {
        int j0 = csr_src[i], j1 = csr_src[i + 1];
        ushort8 u0 = *(const ushort8*)&X[(size_t)j0 * 128 + c8];
        ushort8 u1 = *(const ushort8*)&X[(size_t)j1 * 128 + c8];
#pragma unroll
        for (int k = 0; k < 8; ++k) acc[k] += bf2f(u0[k]) + bf2f(u1[k]);
    }
    if (i < e) {
        int j0 = csr_src[i];
        ushort8 u0 = *(const ushort8*)&X[(size_t)j0 * 128 + c8];
#pragma unroll
        for (int k = 0; k < 8; ++k) acc[k] += bf2f(u0[k]);
    }
    ushort8 o;
    if (AFFINE) {
        float cnt = (float)(e - s + 1);
#pragma unroll
        for (int k = 0; k < 8; ++k) {
            float v = fmaf(ab[c8 + k], acc[k], cnt * ab[128 + c8 + k]);
            o[k] = f2bf(v);
        }
    } else {
#pragma unroll
        for (int k = 0; k < 8; ++k) o[k] = f2bf(acc[k]);
    }
    *(ushort8*)&out[(size_t)node * 128 + c8] = o;
}

// ================= MFMA GEMM: Out = bf16(leaky(A @ W + bias)) ===================
// A [N,128] bf16, WT [128,128] bf16 pre-transposed (WT[n][k] = W[k][n]).
// 128x128 tile per block, K=128 fully LDS-resident, XOR-swizzled chunks.
template<bool STATS>
__global__ __launch_bounds__(256)
void gemm_mfma(const unsigned short* __restrict__ A, const unsigned short* __restrict__ WT,
               const float* __restrict__ bias, unsigned short* __restrict__ Out,
               float* __restrict__ stat_sum, float* __restrict__ stat_sq, int N)
{
    __shared__ unsigned short As[128 * 128];  // 32 KB, chunk (r,g): idx = r*16 + (g^(r&7))
    __shared__ unsigned short Ws[128 * 128];  // 32 KB, same swizzle (row = n)

    const int t = threadIdx.x;
    const int row0 = blockIdx.x * 128;

    {
        int g  = t & 15;     // 16B col-chunk
        int rq = t >> 4;     // row phase
#pragma unroll
        for (int p = 0; p < 8; ++p) {
            int r = p * 16 + rq;
            int chunk = r * 16 + (g ^ (r & 7));
            ushort8 v = {0, 0, 0, 0, 0, 0, 0, 0};
            int gr = row0 + r;
            if (gr < N) v = *(const ushort8*)&A[(size_t)gr * 128 + g * 8];
            *(ushort8*)&As[chunk * 8] = v;
            ushort8 w = *(const ushort8*)&WT[r * 128 + g * 8];
            *(ushort8*)&Ws[chunk * 8] = w;
        }
    }
    __syncthreads();

    const int wave = t >> 6;
    const int lane = t & 63;
    const int m    = lane & 15;
    const int quad = lane >> 4;

    ffrag acc[2][8];
#pragma unroll
    for (int rt = 0; rt < 2; ++rt)
#pragma unroll
        for (int ct = 0; ct < 8; ++ct) {
            ffrag z = {0.f, 0.f, 0.f, 0.f};
            acc[rt][ct] = z;
        }

#pragma unroll
    for (int ks = 0; ks < 4; ++ks) {
        int kc = ks * 4 + quad;          // 8-elem k-chunk index 0..15
        bfrag b[8];
#pragma unroll
        for (int ct = 0; ct < 8; ++ct) {
            int n = ct * 16 + m;
            int chunk = n * 16 + (kc ^ (n & 7));
            b[ct] = *(const bfrag*)&Ws[chunk * 8];
        }
        bfrag a0, a1;
        {
            int r = wave * 32 + m;
            int chunk = r * 16 + (kc ^ (r & 7));
            a0 = *(const bfrag*)&As[chunk * 8];
        }
        {
            int r = wave * 32 + 16 + m;
            int chunk = r * 16 + (kc ^ (r & 7));
            a1 = *(const bfrag*)&As[chunk * 8];
        }
#pragma unroll
        for (int ct = 0; ct < 8; ++ct) {
            acc[0][ct] = __builtin_amdgcn_mfma_f32_16x16x32_bf16(a0, b[ct], acc[0][ct], 0, 0, 0);
            acc[1][ct] = __builtin_amdgcn_mfma_f32_16x16x32_bf16(a1, b[ct], acc[1][ct], 0, 0, 0);
        }
    }

    // epilogue: bias + leaky + bf16 store (+ stats)
    float bv[8];
#pragma unroll
    for (int ct = 0; ct < 8; ++ct) bv[ct] = bias[ct * 16 + m];

    float colsum[8], colsq[8];
#pragma unroll
    for (int ct = 0; ct < 8; ++ct) { colsum[ct] = 0.f; colsq[ct] = 0.f; }

#pragma unroll
    for (int rt = 0; rt < 2; ++rt) {
        int rbase = row0 + wave * 32 + rt * 16 + quad * 4;
#pragma unroll
        for (int reg = 0; reg < 4; ++reg) {
            int r = rbase + reg;
            if (r < N) {
#pragma unroll
                for (int ct = 0; ct < 8; ++ct) {
                    int c = ct * 16 + m;
                    float v = leaky(acc[rt][ct][reg] + bv[ct]);
                    Out[(size_t)r * 128 + c] = f2bf(v);
                    if (STATS) { colsum[ct] += v; colsq[ct] += v * v; }
                }
            }
        }
    }

    if (STATS) {
        __syncthreads();                       // done with As/Ws, reuse as fp32 scratch
        float* ss = (float*)As;
        float* sq = ss + 128;
        if (t < 128) { ss[t] = 0.f; sq[t] = 0.f; }
        __syncthreads();
#pragma unroll
        for (int ct = 0; ct < 8; ++ct) {
            atomicAdd(&ss[ct * 16 + m], colsum[ct]);
            atomicAdd(&sq[ct * 16 + m], colsq[ct]);
        }
        __syncthreads();
        if (t < 128) {
            atomicAdd(&stat_sum[t], ss[t]);
            atomicAdd(&stat_sq[t], sq[t]);
        }
    }
}

// ================= BN finalize ==================================================
__global__ void finalize_bn(const float* __restrict__ sum, const float* __restrict__ sq,
                            const float* __restrict__ g, const float* __restrict__ be,
                            float* __restrict__ ab, int N)
{
    int f = threadIdx.x;
    float invN = 1.f / (float)N;
    float mean = sum[f] * invN;
    float var  = sq[f] * invN - mean * mean;
    float a = g[f] * rsqrtf(var + BN_EPS);
    ab[f]       = a;
    ab[128 + f] = be[f] - a * mean;
}

// ================= pool =========================================================
__device__ __forceinline__ int lower_bound(const int* b, int n, int v)
{
    int lo = 0, hi = n;
    while (lo < hi) { int mid = (lo + hi) >> 1; if (b[mid] < v) lo = mid + 1; else hi = mid; }
    return lo;
}

__global__ __launch_bounds__(128)
void pool_bf(const unsigned short* __restrict__ Hn, const int* __restrict__ batch,
             const float* __restrict__ ab2, float* __restrict__ hg, int N)
{
    int g = blockIdx.x;
    int f = threadIdx.x;
    __shared__ int ss, se;
    if (f == 0) {
        ss = lower_bound(batch, N, g);
        se = lower_bound(batch, N, g + 1);
    }
    __syncthreads();
    float acc = 0.f;
    for (int i = ss; i < se; ++i) acc += bf2f(Hn[(size_t)i * 128 + f]);
    float cnt = (float)(se - ss);
    hg[(size_t)g * 128 + f] = fmaf(ab2[f], acc, cnt * ab2[128 + f]);
}

// ================= head =========================================================
__global__ __launch_bounds__(128)
void head_kernel(const float* __restrict__ hg, const float* __restrict__ fcW1,
                 const float* __restrict__ fcb1, const float* __restrict__ fcW2,
                 const float* __restrict__ fcb2, float* __restrict__ out)
{
    int g = blockIdx.x;
    int t = threadIdx.x;
    __shared__ float row[128];
    __shared__ float z1[128];
    row[t] = hg[(size_t)g * 128 + t];
    __syncthreads();
    float acc = fcb1[t];
#pragma unroll 8
    for (int k = 0; k < 128; ++k) acc = fmaf(row[k], fcW1[(size_t)k * 128 + t], acc);
    z1[t] = leaky(acc);
    __syncthreads();
    if (t < 64) {
        float lg[NCLS];
#pragma unroll
        for (int c = 0; c < NCLS; ++c) {
            float p = z1[t] * fcW2[t * NCLS + c] + z1[t + 64] * fcW2[(t + 64) * NCLS + c];
#pragma unroll
            for (int off = 32; off > 0; off >>= 1) p += __shfl_down(p, off, 64);
            if (t == 0) lg[c] = p + fcb2[c];
        }
        if (t == 0) {
            float m = lg[0];
#pragma unroll
            for (int c = 1; c < NCLS; ++c) m = fmaxf(m, lg[c]);
            float s = 0.f;
#pragma unroll
            for (int c = 0; c < NCLS; ++c) s += expf(lg[c] - m);
            float lse = logf(s);
#pragma unroll
            for (int c = 0; c < NCLS; ++c) out[(size_t)g * NCLS + c] = lg[c] - m - lse;
        }
    }
}

// ================= launch =======================================================
extern "C" void kernel_launch(void* const* d_in, const int* in_sizes, int n_in,
                              void* d_out, int out_size, void* d_ws, size_t ws_size,
                              hipStream_t stream)
{
    const float* x    = (const float*)d_in[0];
    const float* W1a  = (const float*)d_in[1];
    const float* b1a  = (const float*)d_in[2];
    const float* W1b  = (const float*)d_in[3];
    const float* b1b  = (const float*)d_in[4];
    const float* g1   = (const float*)d_in[5];
    const float* be1  = (const float*)d_in[6];
    const float* W2a  = (const float*)d_in[7];
    const float* b2a  = (const float*)d_in[8];
    const float* W2b  = (const float*)d_in[9];
    const float* b2b  = (const float*)d_in[10];
    const float* g2   = (const float*)d_in[11];
    const float* be2  = (const float*)d_in[12];
    const float* fcW1 = (const float*)d_in[13];
    const float* fcb1 = (const float*)d_in[14];
    const float* fcW2 = (const float*)d_in[15];
    const float* fcb2 = (const float*)d_in[16];
    const int*   edge = (const int*)d_in[17];
    const int*   batch= (const int*)d_in[18];

    const int N = in_sizes[0] / 128;
    const int E = in_sizes[17] / 2;
    const int* src = edge;
    const int* dst = edge + E;
    const size_t NH = (size_t)N * 128;

    float* fws   = (float*)d_ws;
    float* stats = fws;               // sum1,sq1,sum2,sq2 (512)
    float* sum1  = stats;
    float* sq1   = stats + 128;
    float* sum2  = stats + 256;
    float* sq2   = stats + 384;
    float* ab1   = fws + 512;         // alpha1,beta1
    float* ab2   = fws + 768;         // alpha2,beta2
    float* hg    = fws + 1024;        // [1024,128]
    int*   rowptr = (int*)(hg + (size_t)NUM_GRAPHS * 128);
    int*   rank   = rowptr + ((N + 8) & ~3);
    int*   csr    = rank + ((E + 4) & ~3);
    int*   bsums  = csr + ((E + 4) & ~3);     // 128
    int*   deg    = bsums + 128;
    unsigned short* xb   = (unsigned short*)(deg + ((N + 4) & ~3));
    unsigned short* bufA = xb + NH;
    unsigned short* bufB = bufA + NH;
    unsigned short* wt   = bufB + NH;         // 4 x 16384 bf16, transposed
    unsigned short* wt1a = wt;
    unsigned short* wt1b = wt + 16384;
    unsigned short* wt2a = wt + 32768;
    unsigned short* wt2b = wt + 49152;

    const int edgeBlocks   = (E + 255) / 256;
    const int nodeBlocks   = (N + 255) / 256;
    const int scanBlocks   = (N + 1023) / 1024;
    const int gatherBlocks = (N + 15) / 16;
    const int gemmBlocks   = (N + 127) / 128;
    const int cvtBlocks    = (int)((NH / 4 + 255) / 256);

    hipMemsetAsync(deg, 0, (size_t)N * sizeof(int), stream);
    hipMemsetAsync(stats, 0, 512 * sizeof(float), stream);

    // dtype prep
    cvt_x_kernel<<<cvtBlocks, 256, 0, stream>>>(x, xb, (int)NH);
    cvt_w_kernel<<<4, 256, 0, stream>>>(W1a, W1b, W2a, W2b, wt);

    // CSR build (one atomic pass)
    rank_kernel<<<edgeBlocks, 256, 0, stream>>>(dst, deg, rank, E);
    scan_block_kernel<<<scanBlocks, 256, 0, stream>>>(deg, rowptr, bsums, N);
    scan_sums_kernel<<<1, 128, 0, stream>>>(bsums, scanBlocks);
    add_offsets_kernel<<<nodeBlocks, 256, 0, stream>>>(rowptr, bsums, N, E);
    fill_kernel<<<edgeBlocks, 256, 0, stream>>>(src, dst, rowptr, rank, csr, E);

    // conv1
    gather_bf<false><<<gatherBlocks, 256, 0, stream>>>(xb, rowptr, csr, nullptr, bufA, N);
    gemm_mfma<false><<<gemmBlocks, 256, 0, stream>>>(bufA, wt1a, b1a, bufB, nullptr, nullptr, N);
    gemm_mfma<true><<<gemmBlocks, 256, 0, stream>>>(bufB, wt1b, b1b, bufA, sum1, sq1, N);
    finalize_bn<<<1, 128, 0, stream>>>(sum1, sq1, g1, be1, ab1, N);

    // conv2 (BN1 folded into gather epilogue)
    gather_bf<true><<<gatherBlocks, 256, 0, stream>>>(bufA, rowptr, csr, ab1, bufB, N);
    gemm_mfma<false><<<gemmBlocks, 256, 0, stream>>>(bufB, wt2a, b2a, bufA, nullptr, nullptr, N);
    gemm_mfma<true><<<gemmBlocks, 256, 0, stream>>>(bufA, wt2b, b2b, bufB, sum2, sq2, N);
    finalize_bn<<<1, 128, 0, stream>>>(sum2, sq2, g2, be2, ab2, N);

    // pool (BN2 folded) + head
    pool_bf<<<NUM_GRAPHS, 128, 0, stream>>>(bufB, batch, ab2, hg, N);
    head_kernel<<<NUM_GRAPHS, 128, 0, stream>>>(hg, fcW1, fcb1, fcW2, fcb2, (float*)d_out);
}